// Round 1
// baseline (542.394 us; speedup 1.0000x reference)
//
#include <hip/hip_runtime.h>

typedef __attribute__((ext_vector_type(8))) short short8;
typedef __attribute__((ext_vector_type(4))) float floatx4;
typedef __attribute__((ext_vector_type(4))) unsigned int uintx4;

__device__ __forceinline__ short f2bf(float f) {
    unsigned u = __builtin_bit_cast(unsigned, f);
    u = (u + 0x7FFFu + ((u >> 16) & 1u)) >> 16;
    return (short)u;
}

// ---------------------------------------------------------------------------
// Prep: convert+transpose fp32 w[K][256] -> bf16 wT[256][K] in workspace.
// ws element offsets: w1T0=0, w1T1=65536, w1T2=196608, w2T0=458752,
//                     w2T1=524288, w2T2=589824  (total 655360 bf16 = 1.31MB)
// ---------------------------------------------------------------------------
__global__ __launch_bounds__(256) void prep_w(
    const float* __restrict__ w10, const float* __restrict__ w11, const float* __restrict__ w12,
    const float* __restrict__ w20, const float* __restrict__ w21, const float* __restrict__ w22,
    unsigned short* __restrict__ wsb)
{
    __shared__ float tile[32][33];
    int blk = blockIdx.x;
    const float* in; unsigned short* out; int K, t0;
    if (blk < 64)       { in = w10; out = wsb;          K = 256;  t0 = 0; }
    else if (blk < 192) { in = w11; out = wsb + 65536;  K = 512;  t0 = 64; }
    else if (blk < 448) { in = w12; out = wsb + 196608; K = 1024; t0 = 192; }
    else if (blk < 512) { in = w20; out = wsb + 458752; K = 256;  t0 = 448; }
    else if (blk < 576) { in = w21; out = wsb + 524288; K = 256;  t0 = 512; }
    else                { in = w22; out = wsb + 589824; K = 256;  t0 = 576; }
    int tile_id = blk - t0;
    int tk = K >> 5;
    int k0 = (tile_id % tk) << 5;
    int n0 = (tile_id / tk) << 5;
    int t = threadIdx.x;
    int j = t & 31, i0 = (t >> 5) << 2;
    #pragma unroll
    for (int u = 0; u < 4; u++)
        tile[i0 + u][j] = in[(size_t)(k0 + i0 + u) * 256 + (n0 + j)];
    __syncthreads();
    int kf = t & 31, nf0 = (t >> 5) << 2;
    #pragma unroll
    for (int u = 0; u < 4; u++)
        out[(size_t)(n0 + nf0 + u) * K + (k0 + kf)] = (unsigned short)f2bf(tile[kf][nf0 + u]);
}

// ---------------------------------------------------------------------------
// Fused gather + MLP(2-layer, relu) + L2-normalize.
// Block: 32 rows x 256 cols. 4 waves: wave w -> rows (w&1)*16, cols (w>>1)*128.
// LDS (bytes):  ws  [256][72] bf16 = 36864   @ 0      (w-tile, restaged per chunk)
//               xs  [ 32][72] bf16 =  4608   @ 36864  (gathered A tile, GEMM1)
//               hs  [ 32][264] bf16 = 16896  @ 36864  (h tile, GEMM2; reuses xs)
//               rs  [32] f32        =  128   @ 53760  (row sumsq)
// Strides 72/264 bf16: 16B-aligned rows; start-bank stride 4 dw -> <=2-way (free).
// ---------------------------------------------------------------------------
__global__ __launch_bounds__(256, 2) void fused_mlp(
    const float* __restrict__ feat0, const float* __restrict__ feat1, const float* __restrict__ feat2,
    const int* __restrict__ pid0, const int* __restrict__ pid1, const int* __restrict__ pid2,
    const float* __restrict__ b1_0, const float* __restrict__ b1_1, const float* __restrict__ b1_2,
    const float* __restrict__ b2_0, const float* __restrict__ b2_1, const float* __restrict__ b2_2,
    const unsigned short* __restrict__ wsb,
    float* __restrict__ out)
{
    __shared__ __align__(16) unsigned short smem[26944];
    unsigned short* wsS = smem;            // 256*72
    unsigned short* xs  = smem + 18432;    // 32*72
    unsigned short* hs  = smem + 18432;    // 32*264
    float* rs = (float*)(smem + 26880);    // 32 floats

    int blk = blockIdx.x;
    int scale = 2 - (blk >> 7);            // big-K blocks dispatched first
    int mblk = blk & 127;

    const float* feat; const int* pid; const float* b1; const float* b2;
    const unsigned short* w1T; const unsigned short* w2T;
    int C, HW; size_t outBase;
    if (scale == 0) { feat = feat0; pid = pid0; b1 = b1_0; b2 = b2_0;
                      w1T = wsb;          w2T = wsb + 458752; C = 256;  HW = 16384; outBase = 0; }
    else if (scale == 1) { feat = feat1; pid = pid1; b1 = b1_1; b2 = b2_1;
                      w1T = wsb + 65536;  w2T = wsb + 524288; C = 512;  HW = 4096;  outBase = 1048576; }
    else            { feat = feat2; pid = pid2; b1 = b1_2; b2 = b2_2;
                      w1T = wsb + 196608; w2T = wsb + 589824; C = 1024; HW = 1024;  outBase = 2097152; }

    int t = threadIdx.x;
    int wid = t >> 6, lane = t & 63, quad = lane >> 4, l15 = lane & 15;
    int r0 = (wid & 1) << 4;          // row offset of this wave
    int c0 = (wid >> 1) << 7;         // col offset of this wave

    // gather assignment: thread t loads row gr, k-run [gk, gk+8) of each chunk
    int gr = t >> 3;                  // 0..31
    int gk = (t & 7) << 3;            // 0,8,...,56
    int row_g = (mblk << 5) + gr;
    int bb = row_g >> 8, pp = row_g & 255;
    int s = pid[pp];
    const float* fbase = feat + (size_t)bb * ((size_t)C * HW) + s;

    floatx4 acc[8];
    #pragma unroll
    for (int f = 0; f < 8; f++) acc[f] = (floatx4){0.f, 0.f, 0.f, 0.f};

    // ---------------- GEMM1: x[32,C] @ w1[C,256] ----------------
    for (int kc = 0; kc < C; kc += 64) {
        // stage gathered x chunk (bf16)
        {
            const float* gp = fbase + (size_t)(kc + gk) * HW;
            float v[8];
            #pragma unroll
            for (int j2 = 0; j2 < 8; j2++) v[j2] = gp[(size_t)j2 * HW];
            short8 sv;
            #pragma unroll
            for (int j2 = 0; j2 < 8; j2++) sv[j2] = f2bf(v[j2]);
            *(short8*)(xs + gr * 72 + gk) = sv;
        }
        // stage w1T chunk: thread t = row n, 128B contiguous
        {
            const uintx4* src = (const uintx4*)(w1T + (size_t)t * C + kc);
            uintx4* dst = (uintx4*)(wsS + t * 72);
            #pragma unroll
            for (int j2 = 0; j2 < 8; j2++) dst[j2] = src[j2];
        }
        __syncthreads();
        const unsigned short* aRow = xs + (r0 + l15) * 72;
        const unsigned short* bRow = wsS + (c0 + l15) * 72;
        #pragma unroll
        for (int ks = 0; ks < 2; ks++) {
            short8 af = *(const short8*)(aRow + ks * 32 + quad * 8);
            #pragma unroll
            for (int f = 0; f < 8; f++) {
                short8 bf = *(const short8*)(bRow + f * (16 * 72) + ks * 32 + quad * 8);
                acc[f] = __builtin_amdgcn_mfma_f32_16x16x32_bf16(af, bf, acc[f], 0, 0, 0);
            }
        }
        __syncthreads();
    }

    // ---------------- h = relu(acc + b1) -> LDS (bf16) ----------------
    {
        float bias1[8];
        #pragma unroll
        for (int f = 0; f < 8; f++) bias1[f] = b1[c0 + f * 16 + l15];
        #pragma unroll
        for (int f = 0; f < 8; f++)
            #pragma unroll
            for (int reg = 0; reg < 4; reg++) {
                float h = fmaxf(acc[f][reg] + bias1[f], 0.f);
                hs[(r0 + quad * 4 + reg) * 264 + (c0 + f * 16 + l15)] = (unsigned short)f2bf(h);
            }
    }

    // ---------------- GEMM2: h[32,256] @ w2[256,256] ----------------
    #pragma unroll
    for (int f = 0; f < 8; f++) acc[f] = (floatx4){0.f, 0.f, 0.f, 0.f};
    const unsigned short* hA = hs + (r0 + l15) * 264;
    for (int kc = 0; kc < 256; kc += 64) {
        {
            const uintx4* src = (const uintx4*)(w2T + (size_t)t * 256 + kc);
            uintx4* dst = (uintx4*)(wsS + t * 72);
            #pragma unroll
            for (int j2 = 0; j2 < 8; j2++) dst[j2] = src[j2];
        }
        __syncthreads();
        const unsigned short* bRow = wsS + (c0 + l15) * 72;
        #pragma unroll
        for (int ks = 0; ks < 2; ks++) {
            short8 af = *(const short8*)(hA + kc + ks * 32 + quad * 8);
            #pragma unroll
            for (int f = 0; f < 8; f++) {
                short8 bf = *(const short8*)(bRow + f * (16 * 72) + ks * 32 + quad * 8);
                acc[f] = __builtin_amdgcn_mfma_f32_16x16x32_bf16(af, bf, acc[f], 0, 0, 0);
            }
        }
        __syncthreads();
    }

    // ---------------- epilogue: y = acc + b2; y / (||y|| + 1e-7) ----------------
    {
        float bias2[8];
        #pragma unroll
        for (int f = 0; f < 8; f++) bias2[f] = b2[c0 + f * 16 + l15];
        float psq[4] = {0.f, 0.f, 0.f, 0.f};
        #pragma unroll
        for (int f = 0; f < 8; f++)
            #pragma unroll
            for (int reg = 0; reg < 4; reg++) {
                float yv = acc[f][reg] + bias2[f];
                acc[f][reg] = yv;
                psq[reg] += yv * yv;
            }
        // reduce across the 16 lanes of each quad
        #pragma unroll
        for (int m = 1; m < 16; m <<= 1)
            #pragma unroll
            for (int reg = 0; reg < 4; reg++)
                psq[reg] += __shfl_xor(psq[reg], m, 16);

        if (t < 32) rs[t] = 0.f;
        __syncthreads();
        if (l15 == 0) {
            #pragma unroll
            for (int reg = 0; reg < 4; reg++)
                atomicAdd(&rs[r0 + quad * 4 + reg], psq[reg]);
        }
        __syncthreads();

        #pragma unroll
        for (int f = 0; f < 8; f++)
            #pragma unroll
            for (int reg = 0; reg < 4; reg++) {
                int row = r0 + quad * 4 + reg;
                float inv = 1.f / (sqrtf(rs[row]) + 1e-7f);
                out[outBase + (size_t)((mblk << 5) + row) * 256 + (c0 + f * 16 + l15)] =
                    acc[f][reg] * inv;
            }
    }
}

extern "C" void kernel_launch(void* const* d_in, const int* in_sizes, int n_in,
                              void* d_out, int out_size, void* d_ws, size_t ws_size,
                              hipStream_t stream)
{
    (void)n_in; (void)out_size; (void)ws_size;
    // setup_inputs() dict order interleaves per scale; fall back to signature
    // order if in_sizes says otherwise.
    bool dict = (in_sizes[1] == 256);
    const float *feat[3], *w1[3], *b1[3], *w2[3], *b2[3];
    const int* pid[3];
    for (int i = 0; i < 3; i++) {
        if (dict) {
            feat[i] = (const float*)d_in[i * 6 + 0];
            pid[i]  = (const int*)  d_in[i * 6 + 1];
            w1[i]   = (const float*)d_in[i * 6 + 2];
            b1[i]   = (const float*)d_in[i * 6 + 3];
            w2[i]   = (const float*)d_in[i * 6 + 4];
            b2[i]   = (const float*)d_in[i * 6 + 5];
        } else {
            feat[i] = (const float*)d_in[i];
            pid[i]  = (const int*)  d_in[3 + i];
            w1[i]   = (const float*)d_in[6 + 4 * i + 0];
            b1[i]   = (const float*)d_in[6 + 4 * i + 1];
            w2[i]   = (const float*)d_in[6 + 4 * i + 2];
            b2[i]   = (const float*)d_in[6 + 4 * i + 3];
        }
    }
    unsigned short* wsb = (unsigned short*)d_ws;
    prep_w<<<640, 256, 0, stream>>>(w1[0], w1[1], w1[2], w2[0], w2[1], w2[2], wsb);
    fused_mlp<<<384, 256, 0, stream>>>(feat[0], feat[1], feat[2],
                                       pid[0], pid[1], pid[2],
                                       b1[0], b1[1], b1[2],
                                       b2[0], b2[1], b2[2],
                                       wsb, (float*)d_out);
}